// Round 3
// baseline (197.146 us; speedup 1.0000x reference)
//
#include <hip/hip_runtime.h>
#include <hip/hip_bf16.h>

// Embedding gather: out[token, :] = w[x[token], :]
// B=8, S=2048 -> 16384 tokens; DIM=1024 fp32; VOCAB=32000.
// 4 tokens per block (4-way ILP): 4 independent index loads, 4 independent
// row loads (float4/lane), 4 non-temporal stores. 256 threads = one row's
// 256 float4s.
#define TPI 4  // tokens per block-iteration

typedef float f32x4 __attribute__((ext_vector_type(4)));  // native vec: nontemporal-builtin-compatible

__global__ __launch_bounds__(256) void embed_gather_kernel(
    const int* __restrict__ x, const float* __restrict__ w,
    float* __restrict__ out, int n_tokens) {
  const int tid = threadIdx.x;
  for (int base = blockIdx.x * TPI; base < n_tokens; base += gridDim.x * TPI) {
    int rows[TPI];
#pragma unroll
    for (int i = 0; i < TPI; ++i) {
      int t = base + i;
      rows[i] = (t < n_tokens) ? x[t] : 0;  // wave-uniform -> s_load, 4 in flight
    }
    f32x4 v[TPI];
#pragma unroll
    for (int i = 0; i < TPI; ++i) {
      const f32x4* src = reinterpret_cast<const f32x4*>(w + (size_t)rows[i] * 1024);
      v[i] = src[tid];  // 4 independent 16B loads in flight
    }
#pragma unroll
    for (int i = 0; i < TPI; ++i) {
      int t = base + i;
      if (t < n_tokens) {
        f32x4* dst = reinterpret_cast<f32x4*>(out + (size_t)t * 1024);
        __builtin_nontemporal_store(v[i], dst + tid);  // streaming store, don't evict w
      }
    }
  }
}

extern "C" void kernel_launch(void* const* d_in, const int* in_sizes, int n_in,
                              void* d_out, int out_size, void* d_ws, size_t ws_size,
                              hipStream_t stream) {
  const int* x = (const int*)d_in[0];     // [B*S] int32 token ids
  const float* w = (const float*)d_in[1]; // [VOCAB, DIM] fp32
  float* out = (float*)d_out;             // [B*S, DIM] fp32
  int n_tokens = in_sizes[0];             // 16384
  int grid = (n_tokens + TPI - 1) / TPI;  // 4096 blocks, one iteration each
  embed_gather_kernel<<<grid, 256, 0, stream>>>(x, w, out, n_tokens);
}